// Round 11
// baseline (96.815 us; speedup 1.0000x reference)
//
#include <hip/hip_runtime.h>
#include <hip/hip_bf16.h>

// Problem constants
#define FIN 250
#define NROWS 129024               // 2048*63
#define NT 8                       // tiles per block
#define NBLK 1008                  // 1008*8 = 8064 16-row tiles, exact

typedef short short8 __attribute__((ext_vector_type(8)));
typedef float f32x4 __attribute__((ext_vector_type(4)));

__device__ __forceinline__ short f2bf(float f) {
    __bf16 b = (__bf16)f;
    return __builtin_bit_cast(short, b);
}

#define WAITV(n) asm volatile("s_waitcnt vmcnt(" #n ")" ::: "memory")
#define WAITL    asm volatile("s_waitcnt lgkmcnt(0)" ::: "memory")
#define HWBAR do { asm volatile("" ::: "memory"); __builtin_amdgcn_s_barrier(); \
                   asm volatile("" ::: "memory"); } while (0)

// Stage one 16-row fp32 x-tile (pitch 1024B, linear) via global_load_lds w16.
// Wave wv stages rows wv*4..wv*4+3 -> exactly 4 vmcnt ops per wave.
__device__ __forceinline__ void stage_tile(const float* __restrict__ x,
                                           const float* __restrict__ xlast,
                                           char* lbuf, int tile, int wv, int lane) {
    #pragma unroll
    for (int i = 0; i < 4; ++i) {
        int r = wv * 4 + i;
        int grow = tile * 16 + r;
        const char* g = (grow == NROWS - 1) ? (const char*)xlast
                                            : (const char*)x + (size_t)grow * 1000u;
        g += lane * 16;
        char* l = lbuf + r * 1024;
        __builtin_amdgcn_global_load_lds(
            (const __attribute__((address_space(1))) void*)g,
            (__attribute__((address_space(3))) void*)l, 16, 0, 0);
    }
}

// Pre-kernel: W^T bf16 image, LINEAR [c(256)][k(256 padded, k-pairs packed)],
// zero-padded rows/cols; plus zero-padded copy of the last x row.
__global__ void __launch_bounds__(256)
wt_prep(const float* __restrict__ W, const float* __restrict__ x,
        unsigned* __restrict__ Wt, float* __restrict__ xlast) {
    int i = blockIdx.x * 256 + threadIdx.x;     // 128 blocks x 256 = 32768 words
    unsigned c  = (unsigned)i >> 7;             // 0..255
    unsigned kp = (unsigned)i & 127u;           // 0..127
    unsigned k0 = 2u * kp;
    unsigned lo = 0u, hi = 0u;
    if (c < FIN) {
        if (k0 < FIN)      lo = (unsigned)(unsigned short)f2bf(W[k0 * FIN + c]);
        if (k0 + 1u < FIN) hi = (unsigned)(unsigned short)f2bf(W[(k0 + 1u) * FIN + c]);
    }
    Wt[(c << 7) + kp] = lo | (hi << 16);
    if (blockIdx.x == 0) {
        int t = threadIdx.x;                    // 256 floats = 1024 B
        xlast[t] = (t < FIN) ? x[(size_t)(NROWS - 1) * FIN + t] : 0.f;
    }
}

// 256-thread blocks, W-frags in registers (AGPR-backed), A repacked to
// conflict-free bf16 fragment layout in LDS. 40960B LDS -> 4 blocks/CU.
__global__ void __launch_bounds__(256, 1)
gat_gemm(const float* __restrict__ x, const unsigned short* __restrict__ Wt,
         const float* __restrict__ xlast, const float* __restrict__ bias,
         float* __restrict__ out)
{
    // [0,32768): fp32 stage double-buffer (2 x 16 rows x 1024B)
    // [32768,40960): bf16 afrag buffer: afrag[kk][slot]*16B, slot = lane^kk
    __shared__ __align__(16) char lds[40960];

    const int tid  = threadIdx.x;
    const int lane = tid & 63;
    const int wv   = tid >> 6;        // 0..3: owns cols wv*64 .. wv*64+63
    const int m    = lane & 15;
    const int kg   = lane >> 4;

    // ---- B-fragments in registers for the whole kernel (loaded once, L2/L3-hot) ----
    short8 b[4][8];
    #pragma unroll
    for (int f = 0; f < 4; ++f)
        #pragma unroll
        for (int kk = 0; kk < 8; ++kk)
            b[f][kk] = *(const short8*)((const char*)Wt
                         + ((size_t)(wv * 64 + f * 16 + m) << 9) + kk * 64 + kg * 16);

    float bc[4];
    #pragma unroll
    for (int f = 0; f < 4; ++f) {
        int c = wv * 64 + f * 16 + m;
        bc[f] = (c < FIN) ? bias[c] : 0.f;
    }

    char* const afr = lds + 32768;
    // repack writer decomposition: lane holds k = 4*lane .. 4*lane+3
    const int wkk   = lane >> 3;          // frag kk
    const int wkg   = (lane >> 1) & 3;    // frag kg
    const int whalf = lane & 1;           // frag half (j 0-3 vs 4-7)

    const int t0 = blockIdx.x * NT;
    stage_tile(x, xlast, lds, t0, wv, lane);

    #pragma unroll 1
    for (int i = 0; i < NT; ++i) {
        const int t = t0 + i;
        // Issue next stage, then drain current (counted: 16 stores + 4 stages newer).
        if (i + 1 < NT) {
            stage_tile(x, xlast, lds + ((i + 1) & 1) * 16384, t + 1, wv, lane);
            if (i == 0) { WAITV(4); } else { WAITV(20); }
        } else {
            WAITV(16);
        }
        HWBAR;                          // stage(t) visible; afrag(t-1) fully consumed

        // ---- repack: rows wv*4..wv*4+3, fp32 row-linear read -> bf16 frag write ----
        {
            const char* sb = lds + (i & 1) * 16384;
            #pragma unroll
            for (int rr = 0; rr < 4; ++rr) {
                int row = wv * 4 + rr;
                float4 v = *(const float4*)(sb + row * 1024 + lane * 16);
                unsigned lo = (unsigned)(unsigned short)f2bf(v.x)
                            | ((unsigned)(unsigned short)f2bf(v.y) << 16);
                unsigned hi = (unsigned)(unsigned short)f2bf(v.z)
                            | ((unsigned)(unsigned short)f2bf(v.w) << 16);
                uint2 pk = make_uint2(lo, hi);
                *(uint2*)(afr + wkk * 1024 + wkg * 256 + ((row ^ wkk) * 16) + whalf * 8) = pk;
            }
        }
        WAITL;
        HWBAR;                          // afrag(t) ready for all waves

        // ---- compute: 8 kk x 4 col-frags; A-read = 1 conflict-free b128 per kk ----
        f32x4 acc[4];
        #pragma unroll
        for (int f = 0; f < 4; ++f) acc[f] = (f32x4){bc[f], bc[f], bc[f], bc[f]};
        #pragma unroll
        for (int kk = 0; kk < 8; ++kk) {
            short8 af = *(const short8*)(afr + kk * 1024 + kg * 256 + ((m ^ kk) * 16));
            #pragma unroll
            for (int f = 0; f < 4; ++f)
                acc[f] = __builtin_amdgcn_mfma_f32_16x16x32_bf16(af, b[f][kk], acc[f], 0, 0, 0);
        }

        // ---- stores: 16 global_store_dword per wave (uniform count for vmcnt math) ----
        // C/D layout: col = lane&15 (=m), row = kg*4 + j
        unsigned obase = ((unsigned)t * 16 + (unsigned)kg * 4) * FIN + (unsigned)(wv * 64 + m);
        #pragma unroll
        for (int f = 0; f < 4; ++f) {
            bool ok = (wv < 3) || (f < 3) || (m < 10);   // mask cols 250..255
            if (ok) {
                #pragma unroll
                for (int j = 0; j < 4; ++j)
                    out[obase + (unsigned)(f * 16) + (unsigned)(j * FIN)] = acc[f][j];
            }
        }
    }
}

// 63-node GAT attention over rows 0..62 of out (holding h+bias). Exact: uniform
// logit shifts cancel in softmax and sum(alpha)=1 folds the bias through the mix.
__global__ void __launch_bounds__(1024, 1)
gat_attn(const float* __restrict__ att_src, const float* __restrict__ att_dst,
         float* __restrict__ out)
{
    __shared__ float hs[63 * 252];
    __shared__ float asrc[64], adst[64];
    __shared__ float alpha[63 * 64];

    const int tid = threadIdx.x;

    for (int idx = tid; idx < 63 * FIN; idx += 1024) {
        int r = idx / FIN, f = idx - r * FIN;
        hs[r * 252 + f] = out[idx];
    }
    __syncthreads();

    {   // logits: 16 threads per row, shfl-reduce
        int r = tid >> 4, t = tid & 15;
        float s1 = 0.f, s2 = 0.f;
        if (r < 63) {
            for (int k = t; k < FIN; k += 16) {
                float h = hs[r * 252 + k];
                s1 += h * att_src[k];
                s2 += h * att_dst[k];
            }
        }
        #pragma unroll
        for (int o = 8; o >= 1; o >>= 1) {
            s1 += __shfl_xor(s1, o, 16);
            s2 += __shfl_xor(s2, o, 16);
        }
        if (r < 63 && t == 0) { asrc[r] = s1; adst[r] = s2; }
    }
    __syncthreads();

    {   // softmax per dst row: 16 threads per row
        int d = tid >> 4, t = tid & 15;
        if (d < 63) {
            float ad = adst[d];
            float e_[4];
            float mx = -1e30f;
            #pragma unroll
            for (int q = 0; q < 4; ++q) {
                int sdx = t + q * 16;
                float e = -1e30f;
                if (sdx < 63) {
                    e = asrc[sdx] + ad;
                    e = e > 0.f ? e : 0.2f * e;     // leaky_relu slope 0.2
                }
                e_[q] = e;
                mx = fmaxf(mx, e);
            }
            #pragma unroll
            for (int o = 8; o >= 1; o >>= 1) mx = fmaxf(mx, __shfl_xor(mx, o, 16));
            float den = 0.f;
            #pragma unroll
            for (int q = 0; q < 4; ++q) {
                int sdx = t + q * 16;
                float ex = (sdx < 63) ? __expf(e_[q] - mx) : 0.f;
                e_[q] = ex;
                den += ex;
            }
            #pragma unroll
            for (int o = 8; o >= 1; o >>= 1) den += __shfl_xor(den, o, 16);
            float rd = 1.f / den;
            #pragma unroll
            for (int q = 0; q < 4; ++q) {
                int sdx = t + q * 16;
                if (sdx < 63) alpha[d * 64 + sdx] = e_[q] * rd;
            }
        }
    }
    __syncthreads();

    for (int idx = tid; idx < 63 * FIN; idx += 1024) {
        int d = idx / FIN, f = idx - d * FIN;
        float v = 0.f;
        for (int sdx = 0; sdx < 63; ++sdx)
            v += alpha[d * 64 + sdx] * hs[sdx * 252 + f];
        out[idx] = v;
    }
}

extern "C" void kernel_launch(void* const* d_in, const int* in_sizes, int n_in,
                              void* d_out, int out_size, void* d_ws, size_t ws_size,
                              hipStream_t stream) {
    (void)in_sizes; (void)n_in; (void)ws_size; (void)out_size;
    const float* x        = (const float*)d_in[0];
    const float* W        = (const float*)d_in[1];
    const float* att_src  = (const float*)d_in[2];
    const float* att_dst  = (const float*)d_in[3];
    const float* bias     = (const float*)d_in[4];
    float* out            = (float*)d_out;
    unsigned* Wt          = (unsigned*)d_ws;                       // 128 KiB image
    float* xlast          = (float*)((char*)d_ws + 131072);        // 1 KiB padded row

    wt_prep<<<128, 256, 0, stream>>>(W, x, Wt, xlast);
    gat_gemm<<<NBLK, 256, 0, stream>>>(x, (const unsigned short*)Wt, xlast, bias, out);
    gat_attn<<<1, 1024, 0, stream>>>(att_src, att_dst, out);
}

// Round 12
// 96.456 us; speedup vs baseline: 1.0037x; 1.0037x over previous
//
#include <hip/hip_runtime.h>
#include <hip/hip_bf16.h>

// Problem constants
#define FIN 250
#define NROWS 129024               // 2048*63
#define NT 8                       // tiles per block
#define NBLK 1008                  // 1008*8 = 8064 16-row tiles, exact

typedef short short8 __attribute__((ext_vector_type(8)));
typedef float f32x4 __attribute__((ext_vector_type(4)));

__device__ __forceinline__ short f2bf(float f) {
    __bf16 b = (__bf16)f;
    return __builtin_bit_cast(short, b);
}

#define WAITV(n) asm volatile("s_waitcnt vmcnt(" #n ")" ::: "memory")
#define WAITL    asm volatile("s_waitcnt lgkmcnt(0)" ::: "memory")
#define SCHEDF   __builtin_amdgcn_sched_barrier(0)
#define HWBAR do { asm volatile("" ::: "memory"); __builtin_amdgcn_s_barrier(); \
                   asm volatile("" ::: "memory"); } while (0)

// Stage one 16-row fp32 x-tile (pitch 1024B, linear) via global_load_lds w16.
// 8 waves x 2 rows each -> exactly 2 vmcnt ops per wave.
__device__ __forceinline__ void stage_tile(const float* __restrict__ x,
                                           const float* __restrict__ xlast,
                                           char* lbuf, int tile, int wv, int lane) {
    #pragma unroll
    for (int i = 0; i < 2; ++i) {
        int r = wv * 2 + i;
        int grow = tile * 16 + r;
        const char* g = (grow == NROWS - 1) ? (const char*)xlast
                                            : (const char*)x + (size_t)grow * 1000u;
        g += lane * 16;
        char* l = lbuf + r * 1024;
        __builtin_amdgcn_global_load_lds(
            (const __attribute__((address_space(1))) void*)g,
            (__attribute__((address_space(3))) void*)l, 16, 0, 0);
    }
}

// Pre-kernel: W^T bf16 image, LINEAR [c(256)][k(256 padded, k-pairs packed)],
// zero-padded rows/cols; plus zero-padded copy of the last x row.
__global__ void __launch_bounds__(256)
wt_prep(const float* __restrict__ W, const float* __restrict__ x,
        unsigned* __restrict__ Wt, float* __restrict__ xlast) {
    int i = blockIdx.x * 256 + threadIdx.x;     // 128 blocks x 256 = 32768 words
    unsigned c  = (unsigned)i >> 7;             // 0..255
    unsigned kp = (unsigned)i & 127u;           // 0..127
    unsigned k0 = 2u * kp;
    unsigned lo = 0u, hi = 0u;
    if (c < FIN) {
        if (k0 < FIN)      lo = (unsigned)(unsigned short)f2bf(W[k0 * FIN + c]);
        if (k0 + 1u < FIN) hi = (unsigned)(unsigned short)f2bf(W[(k0 + 1u) * FIN + c]);
    }
    Wt[(c << 7) + kp] = lo | (hi << 16);
    if (blockIdx.x == 0) {
        int t = threadIdx.x;                    // 256 floats = 1024 B
        xlast[t] = (t < FIN) ? x[(size_t)(NROWS - 1) * FIN + t] : 0.f;
    }
}

// 512-thr blocks, 8 waves x 32 cols each: b[2][8]=64 AGPR + arch<=64 -> 128 total
// -> 4 waves/SIMD -> 2 blocks/CU (16 waves/CU). Depth-2 prefetch (3 buffers).
__global__ void __launch_bounds__(512, 4)
gat_gemm(const float* __restrict__ x, const unsigned short* __restrict__ Wt,
         const float* __restrict__ xlast, const float* __restrict__ bias,
         float* __restrict__ out)
{
    // [0,49152): fp32 stage triple-buffer (3 x 16 rows x 1024B)
    // [49152,57344): bf16 afrag buffer: afrag[kk][kg][slot]*16B, slot = row^kk
    __shared__ __align__(16) char lds[57344];

    const int tid  = threadIdx.x;
    const int lane = tid & 63;
    const int wv   = tid >> 6;        // 0..7: owns cols wv*32 .. wv*32+31
    const int m    = lane & 15;
    const int kg   = lane >> 4;

    // ---- B-fragments in registers for the whole kernel (loaded once, L2/L3-hot) ----
    short8 b[2][8];
    #pragma unroll
    for (int f = 0; f < 2; ++f)
        #pragma unroll
        for (int kk = 0; kk < 8; ++kk)
            b[f][kk] = *(const short8*)((const char*)Wt
                         + ((size_t)(wv * 32 + f * 16 + m) << 9) + kk * 64 + kg * 16);

    const int c0 = wv * 32 + m;             // <= 239: always valid
    const float bc0 = bias[c0];
    const float bc1 = (c0 + 16 < FIN) ? bias[c0 + 16] : 0.f;

    char* const afr = lds + 49152;
    // repack writer decomposition: lane holds k = 4*lane .. 4*lane+3 of its row
    const int wkk   = lane >> 3;          // frag kk
    const int wkg   = (lane >> 1) & 3;    // frag kg
    const int whalf = lane & 1;           // frag half (j 0-3 vs 4-7)

    WAITV(0); SCHEDF;                     // b/bias loads drained: clean vmcnt ledger

    const int t0 = blockIdx.x * NT;
    stage_tile(x, xlast, lds,         t0,     wv, lane);
    stage_tile(x, xlast, lds + 16384, t0 + 1, wv, lane);

    #pragma unroll 1
    for (int i = 0; i < NT; ++i) {
        const int t = t0 + i;
        if (i + 2 < NT)
            stage_tile(x, xlast, lds + ((i + 2) % 3) * 16384, t + 2, wv, lane);
        // Counted drain of stage(t). Per-wave ledger (2 stages, 8 stores per iter):
        // newer-than-stage(i) = stores(i-2) + stage(i+1) + stores(i-1) + stage(i+2).
        switch (i) {
            case 0:      WAITV(4);  break;   // stage(1)+stage(2)
            case 1:      WAITV(12); break;   // stage(2)+stores(0)+stage(3)
            case NT - 2: WAITV(18); break;   // no stage(NT)
            case NT - 1: WAITV(16); break;   // no stage(NT),stage(NT+1)
            default:     WAITV(20); break;
        }
        SCHEDF;
        HWBAR;                          // stage(t) visible to all waves

        // ---- repack: rows wv*2, wv*2+1: fp32 row-linear read -> bf16 frag write ----
        {
            const char* sb = lds + (i % 3) * 16384;
            #pragma unroll
            for (int rr = 0; rr < 2; ++rr) {
                int row = wv * 2 + rr;
                float4 v = *(const float4*)(sb + row * 1024 + lane * 16);
                unsigned lo = (unsigned)(unsigned short)f2bf(v.x)
                            | ((unsigned)(unsigned short)f2bf(v.y) << 16);
                unsigned hi = (unsigned)(unsigned short)f2bf(v.z)
                            | ((unsigned)(unsigned short)f2bf(v.w) << 16);
                uint2 pk = make_uint2(lo, hi);
                *(uint2*)(afr + wkk * 1024 + wkg * 256 + ((row ^ wkk) * 16) + whalf * 8) = pk;
            }
        }
        WAITL;
        HWBAR;                          // afrag(t) ready for all waves

        // ---- compute: 8 kk x 2 col-frags; A-read = 1 conflict-free b128 per kk ----
        f32x4 acc0 = {bc0, bc0, bc0, bc0};
        f32x4 acc1 = {bc1, bc1, bc1, bc1};
        #pragma unroll
        for (int kk = 0; kk < 8; ++kk) {
            short8 af = *(const short8*)(afr + kk * 1024 + kg * 256 + ((m ^ kk) * 16));
            acc0 = __builtin_amdgcn_mfma_f32_16x16x32_bf16(af, b[0][kk], acc0, 0, 0, 0);
            acc1 = __builtin_amdgcn_mfma_f32_16x16x32_bf16(af, b[1][kk], acc1, 0, 0, 0);
        }

        // ---- stores: exactly 8 global_store_dword per wave (vmcnt ledger) ----
        // C/D layout: col = lane&15 (=m), row = kg*4 + j
        unsigned obase = ((unsigned)t * 16 + (unsigned)kg * 4) * FIN + (unsigned)(wv * 32 + m);
        #pragma unroll
        for (int j = 0; j < 4; ++j) out[obase + (unsigned)(j * FIN)] = acc0[j];
        if (wv < 7 || m < 10) {         // mask cols 250..255 (exec-masked, still issued)
            #pragma unroll
            for (int j = 0; j < 4; ++j) out[obase + 16u + (unsigned)(j * FIN)] = acc1[j];
        }
    }
}

// 63-node GAT attention over rows 0..62 of out (holding h+bias). Exact: uniform
// logit shifts cancel in softmax and sum(alpha)=1 folds the bias through the mix.
__global__ void __launch_bounds__(1024, 1)
gat_attn(const float* __restrict__ att_src, const float* __restrict__ att_dst,
         float* __restrict__ out)
{
    __shared__ float hs[63 * 252];
    __shared__ float asrc[64], adst[64];
    __shared__ float alpha[63 * 64];

    const int tid = threadIdx.x;

    for (int idx = tid; idx < 63 * FIN; idx += 1024) {
        int r = idx / FIN, f = idx - r * FIN;
        hs[r * 252 + f] = out[idx];
    }
    __syncthreads();

    {   // logits: 16 threads per row, shfl-reduce
        int r = tid >> 4, t = tid & 15;
        float s1 = 0.f, s2 = 0.f;
        if (r < 63) {
            for (int k = t; k < FIN; k += 16) {
                float h = hs[r * 252 + k];
                s1 += h * att_src[k];
                s2 += h * att_dst[k];
            }
        }
        #pragma unroll
        for (int o = 8; o >= 1; o >>= 1) {
            s1 += __shfl_xor(s1, o, 16);
            s2 += __shfl_xor(s2, o, 16);
        }
        if (r < 63 && t == 0) { asrc[r] = s1; adst[r] = s2; }
    }
    __syncthreads();

    {   // softmax per dst row: 16 threads per row
        int d = tid >> 4, t = tid & 15;
        if (d < 63) {
            float ad = adst[d];
            float e_[4];
            float mx = -1e30f;
            #pragma unroll
            for (int q = 0; q < 4; ++q) {
                int sdx = t + q * 16;
                float e = -1e30f;
                if (sdx < 63) {
                    e = asrc[sdx] + ad;
                    e = e > 0.f ? e : 0.2f * e;     // leaky_relu slope 0.2
                }
                e_[q] = e;
                mx = fmaxf(mx, e);
            }
            #pragma unroll
            for (int o = 8; o >= 1; o >>= 1) mx = fmaxf(mx, __shfl_xor(mx, o, 16));
            float den = 0.f;
            #pragma unroll
            for (int q = 0; q < 4; ++q) {
                int sdx = t + q * 16;
                float ex = (sdx < 63) ? __expf(e_[q] - mx) : 0.f;
                e_[q] = ex;
                den += ex;
            }
            #pragma unroll
            for (int o = 8; o >= 1; o >>= 1) den += __shfl_xor(den, o, 16);
            float rd = 1.f / den;
            #pragma unroll
            for (int q = 0; q < 4; ++q) {
                int sdx = t + q * 16;
                if (sdx < 63) alpha[d * 64 + sdx] = e_[q] * rd;
            }
        }
    }
    __syncthreads();

    for (int idx = tid; idx < 63 * FIN; idx += 1024) {
        int d = idx / FIN, f = idx - d * FIN;
        float v = 0.f;
        for (int sdx = 0; sdx < 63; ++sdx)
            v += alpha[d * 64 + sdx] * hs[sdx * 252 + f];
        out[idx] = v;
    }
}

extern "C" void kernel_launch(void* const* d_in, const int* in_sizes, int n_in,
                              void* d_out, int out_size, void* d_ws, size_t ws_size,
                              hipStream_t stream) {
    (void)in_sizes; (void)n_in; (void)ws_size; (void)out_size;
    const float* x        = (const float*)d_in[0];
    const float* W        = (const float*)d_in[1];
    const float* att_src  = (const float*)d_in[2];
    const float* att_dst  = (const float*)d_in[3];
    const float* bias     = (const float*)d_in[4];
    float* out            = (float*)d_out;
    unsigned* Wt          = (unsigned*)d_ws;                       // 128 KiB image
    float* xlast          = (float*)((char*)d_ws + 131072);        // 1 KiB padded row

    wt_prep<<<128, 256, 0, stream>>>(W, x, Wt, xlast);
    gat_gemm<<<NBLK, 512, 0, stream>>>(x, (const unsigned short*)Wt, xlast, bias, out);
    gat_attn<<<1, 1024, 0, stream>>>(att_src, att_dst, out);
}

// Round 13
// 94.736 us; speedup vs baseline: 1.0219x; 1.0182x over previous
//
#include <hip/hip_runtime.h>
#include <hip/hip_bf16.h>

// Problem constants
#define FIN 250
#define NROWS 129024               // 2048*63
#define NT 8                       // tiles per block
#define NBLK 1008                  // 1008*8 = 8064 16-row tiles, exact

typedef short short8 __attribute__((ext_vector_type(8)));
typedef float f32x4 __attribute__((ext_vector_type(4)));

__device__ __forceinline__ short f2bf(float f) {
    __bf16 b = (__bf16)f;
    return __builtin_bit_cast(short, b);
}

#define WAITV(n) asm volatile("s_waitcnt vmcnt(" #n ")" ::: "memory")
#define WAITL    asm volatile("s_waitcnt lgkmcnt(0)" ::: "memory")
#define SCHEDF   __builtin_amdgcn_sched_barrier(0)
#define HWBAR do { asm volatile("" ::: "memory"); __builtin_amdgcn_s_barrier(); \
                   asm volatile("" ::: "memory"); } while (0)

// LDS map
#define AFR_OFF   49152            // bf16 afrag buffer (8 KiB)
#define OUT_OFF   57344            // fp32 out-staging tile, 16 rows x 1024B (16 KiB)

// Stage one 16-row fp32 x-tile (pitch 1024B, linear) via global_load_lds w16.
// 8 waves x 2 rows each -> exactly 2 vmcnt ops per wave.
__device__ __forceinline__ void stage_tile(const float* __restrict__ x,
                                           const float* __restrict__ xlast,
                                           char* lbuf, int tile, int wv, int lane) {
    #pragma unroll
    for (int i = 0; i < 2; ++i) {
        int r = wv * 2 + i;
        int grow = tile * 16 + r;
        const char* g = (grow == NROWS - 1) ? (const char*)xlast
                                            : (const char*)x + (size_t)grow * 1000u;
        g += lane * 16;
        char* l = lbuf + r * 1024;
        __builtin_amdgcn_global_load_lds(
            (const __attribute__((address_space(1))) void*)g,
            (__attribute__((address_space(3))) void*)l, 16, 0, 0);
    }
}

// Pre-kernel: W^T bf16 image, LINEAR [c(256)][k(256 padded, k-pairs packed)],
// zero-padded rows/cols; plus zero-padded copy of the last x row.
__global__ void __launch_bounds__(256)
wt_prep(const float* __restrict__ W, const float* __restrict__ x,
        unsigned* __restrict__ Wt, float* __restrict__ xlast) {
    int i = blockIdx.x * 256 + threadIdx.x;     // 128 blocks x 256 = 32768 words
    unsigned c  = (unsigned)i >> 7;             // 0..255
    unsigned kp = (unsigned)i & 127u;           // 0..127
    unsigned k0 = 2u * kp;
    unsigned lo = 0u, hi = 0u;
    if (c < FIN) {
        if (k0 < FIN)      lo = (unsigned)(unsigned short)f2bf(W[k0 * FIN + c]);
        if (k0 + 1u < FIN) hi = (unsigned)(unsigned short)f2bf(W[(k0 + 1u) * FIN + c]);
    }
    Wt[(c << 7) + kp] = lo | (hi << 16);
    if (blockIdx.x == 0) {
        int t = threadIdx.x;                    // 256 floats = 1024 B
        xlast[t] = (t < FIN) ? x[(size_t)(NROWS - 1) * FIN + t] : 0.f;
    }
}

// 512-thr blocks, 8 waves x 32 cols. b[2][8]=64 AGPR + arch<=64 -> 4 waves/SIMD,
// 2 blocks/CU. Depth-2 prefetch (3 buffers) + LDS-transposed CONTIGUOUS stores.
__global__ void __launch_bounds__(512, 4)
gat_gemm(const float* __restrict__ x, const unsigned short* __restrict__ Wt,
         const float* __restrict__ xlast, const float* __restrict__ bias,
         float* __restrict__ out)
{
    // [0,49152): fp32 stage triple-buffer (3 x 16 rows x 1024B)
    // [49152,57344): bf16 afrag: afrag[kk][kg][slot]*16B, slot = row^kk
    // [57344,73728): fp32 out-staging tile (16 rows x 1024B)
    __shared__ __align__(16) char lds[73728];

    const int tid  = threadIdx.x;
    const int lane = tid & 63;
    const int wv   = tid >> 6;        // 0..7: owns cols wv*32 .. wv*32+31
    const int m    = lane & 15;
    const int kg   = lane >> 4;

    // ---- B-fragments in registers for the whole kernel (loaded once, L2/L3-hot) ----
    short8 b[2][8];
    #pragma unroll
    for (int f = 0; f < 2; ++f)
        #pragma unroll
        for (int kk = 0; kk < 8; ++kk)
            b[f][kk] = *(const short8*)((const char*)Wt
                         + ((size_t)(wv * 32 + f * 16 + m) << 9) + kk * 64 + kg * 16);

    const int c0 = wv * 32 + m;             // <= 239: always valid
    const float bc0 = bias[c0];
    const float bc1 = (c0 + 16 < FIN) ? bias[c0 + 16] : 0.f;

    char* const afr = lds + AFR_OFF;
    char* const ob  = lds + OUT_OFF;
    // repack writer decomposition: lane holds k = 4*lane .. 4*lane+3 of its row
    const int wkk   = lane >> 3;          // frag kk
    const int wkg   = (lane >> 1) & 3;    // frag kg
    const int whalf = lane & 1;           // frag half (j 0-3 vs 4-7)

    WAITV(0); SCHEDF;                     // b/bias loads drained: clean vmcnt ledger

    const int t0 = blockIdx.x * NT;
    stage_tile(x, xlast, lds,         t0,     wv, lane);
    stage_tile(x, xlast, lds + 16384, t0 + 1, wv, lane);

    #pragma unroll 1
    for (int i = 0; i < NT; ++i) {
        const int t = t0 + i;
        if (i + 2 < NT)
            stage_tile(x, xlast, lds + ((i + 2) % 3) * 16384, t + 2, wv, lane);
        // Counted drain of stage(t). Per-wave ledger: 2 stages + 4 stores per iter.
        // steady outstanding at this point: stage(i)2 st(i-2)4 stage(i+1)2 st(i-1)4
        // stage(i+2)2 = 14 -> retire stage(i) -> vmcnt(12).
        switch (i) {
            case 0:      WAITV(4);  break;
            case 1:      WAITV(8);  break;
            case NT - 2: WAITV(10); break;   // stage(NT) not issued
            case NT - 1: WAITV(8);  break;   // stage(NT),stage(NT+1) not issued
            default:     WAITV(12); break;
        }
        SCHEDF;
        HWBAR;                          // stage(t) visible to all waves

        // ---- repack: rows wv*2, wv*2+1: fp32 row-linear read -> bf16 frag write ----
        {
            const char* sb = lds + (i % 3) * 16384;
            #pragma unroll
            for (int rr = 0; rr < 2; ++rr) {
                int row = wv * 2 + rr;
                float4 v = *(const float4*)(sb + row * 1024 + lane * 16);
                unsigned lo = (unsigned)(unsigned short)f2bf(v.x)
                            | ((unsigned)(unsigned short)f2bf(v.y) << 16);
                unsigned hi = (unsigned)(unsigned short)f2bf(v.z)
                            | ((unsigned)(unsigned short)f2bf(v.w) << 16);
                uint2 pk = make_uint2(lo, hi);
                *(uint2*)(afr + wkk * 1024 + wkg * 256 + ((row ^ wkk) * 16) + whalf * 8) = pk;
            }
        }
        WAITL;
        HWBAR;                          // afrag(t) ready for all waves

        // ---- compute: 8 kk x 2 col-frags; A-read = 1 conflict-free b128 per kk ----
        f32x4 acc0 = {bc0, bc0, bc0, bc0};
        f32x4 acc1 = {bc1, bc1, bc1, bc1};
        #pragma unroll
        for (int kk = 0; kk < 8; ++kk) {
            short8 af = *(const short8*)(afr + kk * 1024 + kg * 256 + ((m ^ kk) * 16));
            acc0 = __builtin_amdgcn_mfma_f32_16x16x32_bf16(af, b[0][kk], acc0, 0, 0, 0);
            acc1 = __builtin_amdgcn_mfma_f32_16x16x32_bf16(af, b[1][kk], acc1, 0, 0, 0);
        }

        // ---- out-stage: acc -> LDS tile (row-major, pitch 1024) ----
        // C/D layout: col = lane&15 (=m), row = kg*4 + j
        #pragma unroll
        for (int j = 0; j < 4; ++j) {
            *(float*)(ob + (kg * 4 + j) * 1024 + (unsigned)(wv * 32 + m) * 4)      = acc0[j];
            *(float*)(ob + (kg * 4 + j) * 1024 + (unsigned)(wv * 32 + 16 + m) * 4) = acc1[j];
        }
        WAITL;
        HWBAR;                          // all waves' fragments staged

        // ---- contiguous stores: 2 rows per wave, 1KB-linear bursts ----
        #pragma unroll
        for (int rr = 0; rr < 2; ++rr) {
            int row = wv * 2 + rr;
            float4 v = *(const float4*)(ob + row * 1024 + lane * 16);
            char* op = (char*)out + ((size_t)t * 16 + row) * 1000u;
            if (lane < 62)  *(float4*)(op + lane * 16) = v;          // bytes 0..992
            if (lane == 62) *(float2*)(op + 992) = make_float2(v.x, v.y);  // 992..1000
        }
    }
}

// 63-node GAT attention over rows 0..62 of out (holding h+bias). Exact: uniform
// logit shifts cancel in softmax and sum(alpha)=1 folds the bias through the mix.
__global__ void __launch_bounds__(1024, 1)
gat_attn(const float* __restrict__ att_src, const float* __restrict__ att_dst,
         float* __restrict__ out)
{
    __shared__ float hs[63 * 252];
    __shared__ float asrc[64], adst[64];
    __shared__ float alpha[63 * 64];

    const int tid = threadIdx.x;

    for (int idx = tid; idx < 63 * FIN; idx += 1024) {
        int r = idx / FIN, f = idx - r * FIN;
        hs[r * 252 + f] = out[idx];
    }
    __syncthreads();

    {   // logits: 16 threads per row, shfl-reduce
        int r = tid >> 4, t = tid & 15;
        float s1 = 0.f, s2 = 0.f;
        if (r < 63) {
            for (int k = t; k < FIN; k += 16) {
                float h = hs[r * 252 + k];
                s1 += h * att_src[k];
                s2 += h * att_dst[k];
            }
        }
        #pragma unroll
        for (int o = 8; o >= 1; o >>= 1) {
            s1 += __shfl_xor(s1, o, 16);
            s2 += __shfl_xor(s2, o, 16);
        }
        if (r < 63 && t == 0) { asrc[r] = s1; adst[r] = s2; }
    }
    __syncthreads();

    {   // softmax per dst row: 16 threads per row
        int d = tid >> 4, t = tid & 15;
        if (d < 63) {
            float ad = adst[d];
            float e_[4];
            float mx = -1e30f;
            #pragma unroll
            for (int q = 0; q < 4; ++q) {
                int sdx = t + q * 16;
                float e = -1e30f;
                if (sdx < 63) {
                    e = asrc[sdx] + ad;
                    e = e > 0.f ? e : 0.2f * e;     // leaky_relu slope 0.2
                }
                e_[q] = e;
                mx = fmaxf(mx, e);
            }
            #pragma unroll
            for (int o = 8; o >= 1; o >>= 1) mx = fmaxf(mx, __shfl_xor(mx, o, 16));
            float den = 0.f;
            #pragma unroll
            for (int q = 0; q < 4; ++q) {
                int sdx = t + q * 16;
                float ex = (sdx < 63) ? __expf(e_[q] - mx) : 0.f;
                e_[q] = ex;
                den += ex;
            }
            #pragma unroll
            for (int o = 8; o >= 1; o >>= 1) den += __shfl_xor(den, o, 16);
            float rd = 1.f / den;
            #pragma unroll
            for (int q = 0; q < 4; ++q) {
                int sdx = t + q * 16;
                if (sdx < 63) alpha[d * 64 + sdx] = e_[q] * rd;
            }
        }
    }
    __syncthreads();

    for (int idx = tid; idx < 63 * FIN; idx += 1024) {
        int d = idx / FIN, f = idx - d * FIN;
        float v = 0.f;
        for (int sdx = 0; sdx < 63; ++sdx)
            v += alpha[d * 64 + sdx] * hs[sdx * 252 + f];
        out[idx] = v;
    }
}

extern "C" void kernel_launch(void* const* d_in, const int* in_sizes, int n_in,
                              void* d_out, int out_size, void* d_ws, size_t ws_size,
                              hipStream_t stream) {
    (void)in_sizes; (void)n_in; (void)ws_size; (void)out_size;
    const float* x        = (const float*)d_in[0];
    const float* W        = (const float*)d_in[1];
    const float* att_src  = (const float*)d_in[2];
    const float* att_dst  = (const float*)d_in[3];
    const float* bias     = (const float*)d_in[4];
    float* out            = (float*)d_out;
    unsigned* Wt          = (unsigned*)d_ws;                       // 128 KiB image
    float* xlast          = (float*)((char*)d_ws + 131072);        // 1 KiB padded row

    wt_prep<<<128, 256, 0, stream>>>(W, x, Wt, xlast);
    gat_gemm<<<NBLK, 512, 0, stream>>>(x, (const unsigned short*)Wt, xlast, bias, out);
    gat_attn<<<1, 1024, 0, stream>>>(att_src, att_dst, out);
}

// Round 14
// 91.389 us; speedup vs baseline: 1.0594x; 1.0366x over previous
//
#include <hip/hip_runtime.h>
#include <hip/hip_bf16.h>

// Problem constants
#define FIN 250
#define NROWS 129024               // 2048*63
#define NT 8                       // tiles per block
#define NBLK 1008                  // 1008*8 = 8064 16-row tiles, exact

typedef short short8 __attribute__((ext_vector_type(8)));
typedef float f32x4 __attribute__((ext_vector_type(4)));

__device__ __forceinline__ short f2bf(float f) {
    __bf16 b = (__bf16)f;
    return __builtin_bit_cast(short, b);
}

#define WAITV(n) asm volatile("s_waitcnt vmcnt(" #n ")" ::: "memory")
#define WAITL    asm volatile("s_waitcnt lgkmcnt(0)" ::: "memory")
#define SCHEDF   __builtin_amdgcn_sched_barrier(0)
#define HWBAR do { asm volatile("" ::: "memory"); __builtin_amdgcn_s_barrier(); \
                   asm volatile("" ::: "memory"); } while (0)

// LDS map (32 KiB/block -> 3+ blocks/CU)
#define AFR0 0                     // bf16 afrag buffer, tile parity 0 (8 KiB)
#define AFR1 8192                  // bf16 afrag buffer, tile parity 1 (8 KiB)
#define OB   16384                 // fp32 out-staging tile, 16 rows x 1024B (16 KiB)

// Issue 4 coalesced 1KB register loads for one tile (wave wv owns rows wv*4..+3).
// Per-lane addr = rowbase + lane*16; overruns past byte 1000 land in the next row
// (in-bounds, feeds k>=250 pad slots which multiply zeroed W columns); the very
// last row is redirected to the 1024B zero-padded xlast copy.
__device__ __forceinline__ void load_tile(uint4 (&lb)[4], const float* __restrict__ x,
                                          const float* __restrict__ xlast,
                                          int tile, int wv, int lane) {
    #pragma unroll
    for (int rr = 0; rr < 4; ++rr) {
        int grow = tile * 16 + wv * 4 + rr;
        const char* g = (grow == NROWS - 1) ? (const char*)xlast
                                            : (const char*)x + (size_t)grow * 1000u;
        lb[rr] = *(const uint4*)(g + lane * 16);
    }
}

// Pre-kernel: W^T bf16 image, LINEAR [c(256)][k(256 padded, k-pairs packed)],
// zero-padded rows/cols; plus zero-padded copy of the last x row.
__global__ void __launch_bounds__(256)
wt_prep(const float* __restrict__ W, const float* __restrict__ x,
        unsigned* __restrict__ Wt, float* __restrict__ xlast) {
    int i = blockIdx.x * 256 + threadIdx.x;     // 128 blocks x 256 = 32768 words
    unsigned c  = (unsigned)i >> 7;             // 0..255
    unsigned kp = (unsigned)i & 127u;           // 0..127
    unsigned k0 = 2u * kp;
    unsigned lo = 0u, hi = 0u;
    if (c < FIN) {
        if (k0 < FIN)      lo = (unsigned)(unsigned short)f2bf(W[k0 * FIN + c]);
        if (k0 + 1u < FIN) hi = (unsigned)(unsigned short)f2bf(W[(k0 + 1u) * FIN + c]);
    }
    Wt[(c << 7) + kp] = lo | (hi << 16);
    if (blockIdx.x == 0) {
        int t = threadIdx.x;                    // 256 floats = 1024 B
        xlast[t] = (t < FIN) ? x[(size_t)(NROWS - 1) * FIN + t] : 0.f;
    }
}

// 256-thr blocks (high-VGPR regime), reg-staged x (NO global_load_lds), fused
// convert+repack into fragment-layout LDS, counted-vmcnt register ping-pong.
__global__ void __launch_bounds__(256, 1)
gat_gemm(const float* __restrict__ x, const unsigned short* __restrict__ Wt,
         const float* __restrict__ xlast, const float* __restrict__ bias,
         float* __restrict__ out)
{
    __shared__ __align__(16) char lds[32768];

    const int tid  = threadIdx.x;
    const int lane = tid & 63;
    const int wv   = tid >> 6;        // 0..3: owns cols wv*64 .. wv*64+63, rows wv*4..+3
    const int m    = lane & 15;
    const int kg   = lane >> 4;

    // ---- B-fragments in registers for the whole kernel (loaded once, L2/L3-hot) ----
    short8 b[4][8];
    #pragma unroll
    for (int f = 0; f < 4; ++f)
        #pragma unroll
        for (int kk = 0; kk < 8; ++kk)
            b[f][kk] = *(const short8*)((const char*)Wt
                         + ((size_t)(wv * 64 + f * 16 + m) << 9) + kk * 64 + kg * 16);

    float bc[4];
    #pragma unroll
    for (int f = 0; f < 4; ++f) {
        int c = wv * 64 + f * 16 + m;
        bc[f] = (c < FIN) ? bias[c] : 0.f;
    }

    char* const ob = lds + OB;
    // repack writer decomposition: lane holds floats k=4*lane..4*lane+3 of each row
    const int wkk   = lane >> 3;          // frag kk
    const int wkg   = (lane >> 1) & 3;    // frag kg
    const int whalf = lane & 1;           // frag half (j 0-3 vs 4-7)
    const unsigned wroff = (unsigned)(wkk * 1024 + wkg * 256 + whalf * 8);

    WAITV(0); SCHEDF;                     // b/bias loads drained: clean vmcnt ledger

    const int t0 = blockIdx.x * NT;
    uint4 lbA[4], lbB[4];                 // register ping-pong tile buffers
    load_tile(lbA, x, xlast, t0,     wv, lane);
    load_tile(lbB, x, xlast, t0 + 1, wv, lane);
    SCHEDF;

    #pragma unroll 1
    for (int i = 0; i < NT; ++i) {
        const int t = t0 + i;
        // Counted drain of loads(t). Ledger (4 loads + 8 stores per iter, loads
        // issued mid-iter i-2): newer = stores(i-2)8 + loads(t+1)4 + stores(i-1)8.
        switch (i) {
            case 0:      WAITV(4);  break;   // loads(t1) only
            case 1:      WAITV(12); break;   // loads(t2)4 + stores(0)8
            case NT - 1: WAITV(16); break;   // loads(tNT) never issued
            default:     WAITV(20); break;
        }
        SCHEDF;

        // ---- convert + repack from registers -> fragment-layout LDS ----
        {
            char* const afrD = lds + ((i & 1) ? AFR1 : AFR0);
            const uint4* lb = (i & 1) ? lbB : lbA;
            #pragma unroll
            for (int rr = 0; rr < 4; ++rr) {
                int row = wv * 4 + rr;
                float v0 = __builtin_bit_cast(float, lb[rr].x);
                float v1 = __builtin_bit_cast(float, lb[rr].y);
                float v2 = __builtin_bit_cast(float, lb[rr].z);
                float v3 = __builtin_bit_cast(float, lb[rr].w);
                unsigned lo = (unsigned)(unsigned short)f2bf(v0)
                            | ((unsigned)(unsigned short)f2bf(v1) << 16);
                unsigned hi = (unsigned)(unsigned short)f2bf(v2)
                            | ((unsigned)(unsigned short)f2bf(v3) << 16);
                *(uint2*)(afrD + wroff + (unsigned)(((row ^ wkk) * 16)))
                    = make_uint2(lo, hi);
            }
        }
        SCHEDF;
        // ---- reissue freed buffer with tile t+2 (in flight across compute) ----
        if (i + 2 < NT) {
            if (i & 1) load_tile(lbB, x, xlast, t + 2, wv, lane);
            else       load_tile(lbA, x, xlast, t + 2, wv, lane);
        }
        SCHEDF;
        WAITL;
        HWBAR;                          // afrag(t) ready for all waves

        // ---- compute: 8 kk x 4 col-frags; conflict-free b128 A-reads ----
        const char* afrD = lds + ((i & 1) ? AFR1 : AFR0);
        f32x4 acc[4];
        #pragma unroll
        for (int f = 0; f < 4; ++f) acc[f] = (f32x4){bc[f], bc[f], bc[f], bc[f]};
        #pragma unroll
        for (int kk = 0; kk < 8; ++kk) {
            short8 af = *(const short8*)(afrD + kk * 1024 + kg * 256 + ((m ^ kk) * 16));
            #pragma unroll
            for (int f = 0; f < 4; ++f)
                acc[f] = __builtin_amdgcn_mfma_f32_16x16x32_bf16(af, b[f][kk], acc[f], 0, 0, 0);
        }

        // ---- out-stage: acc -> LDS tile (row-major, pitch 1024) ----
        // C/D layout: col = lane&15 (=m), row = kg*4 + j
        #pragma unroll
        for (int f = 0; f < 4; ++f)
            #pragma unroll
            for (int j = 0; j < 4; ++j)
                *(float*)(ob + (kg * 4 + j) * 1024 + (unsigned)(wv * 64 + f * 16 + m) * 4)
                    = acc[f][j];
        WAITL;
        HWBAR;                          // all waves' fragments staged

        // ---- contiguous stores: 4 rows per wave, 1KB-linear bursts (8 vmem) ----
        #pragma unroll
        for (int rr = 0; rr < 4; ++rr) {
            int row = wv * 4 + rr;
            float4 v = *(const float4*)(ob + row * 1024 + lane * 16);
            char* op = (char*)out + ((size_t)t * 16 + row) * 1000u;
            if (lane < 62)  *(float4*)(op + lane * 16) = v;                 // 0..992
            if (lane == 62) *(float2*)(op + 992) = make_float2(v.x, v.y);   // 992..1000
        }
    }
}

// 63-node GAT attention over rows 0..62 of out (holding h+bias). Exact: uniform
// logit shifts cancel in softmax and sum(alpha)=1 folds the bias through the mix.
__global__ void __launch_bounds__(1024, 1)
gat_attn(const float* __restrict__ att_src, const float* __restrict__ att_dst,
         float* __restrict__ out)
{
    __shared__ float hs[63 * 252];
    __shared__ float asrc[64], adst[64];
    __shared__ float alpha[63 * 64];

    const int tid = threadIdx.x;

    for (int idx = tid; idx < 63 * FIN; idx += 1024) {
        int r = idx / FIN, f = idx - r * FIN;
        hs[r * 252 + f] = out[idx];
    }
    __syncthreads();

    {   // logits: 16 threads per row, shfl-reduce
        int r = tid >> 4, t = tid & 15;
        float s1 = 0.f, s2 = 0.f;
        if (r < 63) {
            for (int k = t; k < FIN; k += 16) {
                float h = hs[r * 252 + k];
                s1 += h * att_src[k];
                s2 += h * att_dst[k];
            }
        }
        #pragma unroll
        for (int o = 8; o >= 1; o >>= 1) {
            s1 += __shfl_xor(s1, o, 16);
            s2 += __shfl_xor(s2, o, 16);
        }
        if (r < 63 && t == 0) { asrc[r] = s1; adst[r] = s2; }
    }
    __syncthreads();

    {   // softmax per dst row: 16 threads per row
        int d = tid >> 4, t = tid & 15;
        if (d < 63) {
            float ad = adst[d];
            float e_[4];
            float mx = -1e30f;
            #pragma unroll
            for (int q = 0; q < 4; ++q) {
                int sdx = t + q * 16;
                float e = -1e30f;
                if (sdx < 63) {
                    e = asrc[sdx] + ad;
                    e = e > 0.f ? e : 0.2f * e;     // leaky_relu slope 0.2
                }
                e_[q] = e;
                mx = fmaxf(mx, e);
            }
            #pragma unroll
            for (int o = 8; o >= 1; o >>= 1) mx = fmaxf(mx, __shfl_xor(mx, o, 16));
            float den = 0.f;
            #pragma unroll
            for (int q = 0; q < 4; ++q) {
                int sdx = t + q * 16;
                float ex = (sdx < 63) ? __expf(e_[q] - mx) : 0.f;
                e_[q] = ex;
                den += ex;
            }
            #pragma unroll
            for (int o = 8; o >= 1; o >>= 1) den += __shfl_xor(den, o, 16);
            float rd = 1.f / den;
            #pragma unroll
            for (int q = 0; q < 4; ++q) {
                int sdx = t + q * 16;
                if (sdx < 63) alpha[d * 64 + sdx] = e_[q] * rd;
            }
        }
    }
    __syncthreads();

    for (int idx = tid; idx < 63 * FIN; idx += 1024) {
        int d = idx / FIN, f = idx - d * FIN;
        float v = 0.f;
        for (int sdx = 0; sdx < 63; ++sdx)
            v += alpha[d * 64 + sdx] * hs[sdx * 252 + f];
        out[idx] = v;
    }
}

extern "C" void kernel_launch(void* const* d_in, const int* in_sizes, int n_in,
                              void* d_out, int out_size, void* d_ws, size_t ws_size,
                              hipStream_t stream) {
    (void)in_sizes; (void)n_in; (void)ws_size; (void)out_size;
    const float* x        = (const float*)d_in[0];
    const float* W        = (const float*)d_in[1];
    const float* att_src  = (const float*)d_in[2];
    const float* att_dst  = (const float*)d_in[3];
    const float* bias     = (const float*)d_in[4];
    float* out            = (float*)d_out;
    unsigned* Wt          = (unsigned*)d_ws;                       // 128 KiB image
    float* xlast          = (float*)((char*)d_ws + 131072);        // 1 KiB padded row

    wt_prep<<<128, 256, 0, stream>>>(W, x, Wt, xlast);
    gat_gemm<<<NBLK, 256, 0, stream>>>(x, (const unsigned short*)Wt, xlast, bias, out);
    gat_attn<<<1, 1024, 0, stream>>>(att_src, att_dst, out);
}